// Round 12
// baseline (349.180 us; speedup 1.0000x reference)
//
#include <hip/hip_runtime.h>

// VQ-VAE vector quantization, MI355X (gfx950) — 4-kernel pipeline.
// z_e: (8,64,64,64) f32 (B,D,H,W); emb: (8192,64) f32.
// N = 32768 rows (n = b*4096 + h*64 + w), D = 64, K = 8192.
// out (f32 concat): z_q[2097152] | indices[32768] | loss | perplexity | usage
//
// prep -> argmin(MFMA fast pass; per-rgrp last-block fuses the quarter-merge)
//      -> refine1 (np-emulated re-rank of near-tie rows, (row x K-quarter) jobs)
//      -> quant (patch flagged rows + z_q gather + loss; global last-block stats)
// Cross-block handoffs inside a kernel use the canonical pattern:
// all threads __threadfence(); __syncthreads(); tid0 atomicAdd(ctr); last block
// __threadfence() then reads. (G16: device-scope, cross-XCD-safe.)

#define K_CODES   8192
#define DIMV      64
#define IDX_OFF   2097152
#define SCAL_OFF  2129920
#define MARGIN    1e-4f   // flip bound ~4.4e-5; 2.3x headroom

// workspace layout (bytes) — identical footprint to round 10
#define WS_B2    0              // 8192 f32
#define WS_IDX   32768          // 32768 i32
#define WS_CNT   163840         // 8192 i32  (zeroed in prep)
#define WS_LOSS  196608         // 1 f32     (zeroed in prep)
#define WS_FCNT  196612         // 1 i32     (zeroed in prep)
#define WS_DONE  196616         // 1 i32     (zeroed in prep)
#define WS_FLIST 196672         // 32768 i32
#define WS_RGRP  327744         // 256 i32 (zeroed in prep; overlays retired a2)
#define WS_EFRAG 458816         // 2 MB frag-blocked -2e hi/lo
#define WS_ZHI   2555968        // 4 MB
#define WS_ZLO   6750272        // 4 MB
#define WS_P1V   10944576       // 4*32768 f32 (fast partials; np partials after)
#define WS_P2V   11468864       // 4*32768 f32 (head doubles as flag[] post-merge)
#define WS_P1I   11993152       // 4*32768 i32 (ends 12517440)

typedef short s16x8  __attribute__((ext_vector_type(8)));
typedef float f32x4  __attribute__((ext_vector_type(4)));

__device__ __forceinline__ short bf16rne(float x) {
    unsigned u = __float_as_uint(x);
    unsigned r = (u + 0x7FFFu + ((u >> 16) & 1u)) >> 16;
    return (short)r;
}
__device__ __forceinline__ float bf16tof(short s) {
    return __uint_as_float(((unsigned)(unsigned short)s) << 16);
}
__device__ __forceinline__ void gl_lds16(const char* g, char* l) {
    __builtin_amdgcn_global_load_lds(
        (const __attribute__((address_space(1))) unsigned int*)g,
        (__attribute__((address_space(3))) unsigned int*)l, 16, 0, 0);
}
// numpy pairwise-8 sum of squares (strictly rounded, no contraction)
__device__ __forceinline__ float pairwise8_sq(const float* __restrict__ x) {
    float r[8];
#pragma unroll
    for (int j = 0; j < 8; ++j) r[j] = __fmul_rn(x[j], x[j]);
#pragma unroll
    for (int i = 8; i < 64; i += 8)
#pragma unroll
        for (int j = 0; j < 8; ++j)
            r[j] = __fadd_rn(r[j], __fmul_rn(x[i + j], x[i + j]));
    const float s01 = __fadd_rn(r[0], r[1]);
    const float s23 = __fadd_rn(r[2], r[3]);
    const float s45 = __fadd_rn(r[4], r[5]);
    const float s67 = __fadd_rn(r[6], r[7]);
    return __fadd_rn(__fadd_rn(s01, s23), __fadd_rn(s45, s67));
}

// K1: prep. blocks [0,512): z -> bf16 hi/lo (transposed). [512,576): emb frags
// + b2 + zero counters.
__global__ __launch_bounds__(256)
void vq_prep(const float* __restrict__ z_e, const float* __restrict__ emb,
             float* __restrict__ b2, short* __restrict__ zt_hi,
             short* __restrict__ zt_lo, short* __restrict__ efrag,
             int* __restrict__ zero_base, int* __restrict__ rgrp_ctr) {
    const int blk = blockIdx.x;
    const int tid = threadIdx.x;
    if (blk < 512) {
        __shared__ float zs[64][65];
        const int b = blk >> 6, h = blk & 63;
        {
            const int w = tid & 63, dq = tid >> 6;
#pragma unroll
            for (int i = 0; i < 16; ++i) {
                const int dd = dq + i * 4;
                zs[w][dd] = z_e[((b * 64 + dd) << 12) + (h << 6) + w];
            }
        }
        __syncthreads();
        const int w = tid & 63, dq = tid >> 6;
        const int n = blk * 64 + w;
        s16x8 h8[2], l8[2];
#pragma unroll
        for (int i = 0; i < 16; ++i) {
            const float x = zs[w][dq * 16 + i];
            const short hh = bf16rne(x);
            ((short*)h8)[i] = hh;
            ((short*)l8)[i] = bf16rne(x - bf16tof(hh));
        }
        *(s16x8*)(zt_hi + n * DIMV + dq * 16)     = h8[0];
        *(s16x8*)(zt_hi + n * DIMV + dq * 16 + 8) = h8[1];
        *(s16x8*)(zt_lo + n * DIMV + dq * 16)     = l8[0];
        *(s16x8*)(zt_lo + n * DIMV + dq * 16 + 8) = l8[1];
    } else {
        const int zi = (blk - 512) * 256 + tid;     // counts+loss+fcnt+done
        if (zi < 8195) zero_base[zi] = 0;
        if (blk == 575 && tid < 256) rgrp_ctr[tid] = 0;
        if (tid < 128) {
            const int k = (blk - 512) * 128 + tid;
            float v[64];
            const float4* row = (const float4*)(emb + k * DIMV);
#pragma unroll
            for (int i = 0; i < 16; ++i) {
                const float4 q = row[i];
                v[i*4+0] = q.x; v[i*4+1] = q.y; v[i*4+2] = q.z; v[i*4+3] = q.w;
            }
            b2[k] = pairwise8_sq(v);
            const int c = k >> 6, ct = (k >> 4) & 3, lcol = k & 15;
#pragma unroll
            for (int g = 0; g < 8; ++g) {
                s16x8 hv, lv;
#pragma unroll
                for (int j = 0; j < 8; ++j) {
                    const float x = -2.0f * v[g*8 + j];      // exact scale
                    const short hh = bf16rne(x);
                    hv[j] = hh;
                    lv[j] = bf16rne(x - bf16tof(hh));
                }
                const int f  = ct*4 + (g >> 2)*2;
                const int ln = (g & 3)*16 + lcol;
                *(s16x8*)(efrag + c*8192 + f*512     + ln*8) = hv;
                *(s16x8*)(efrag + c*8192 + (f+1)*512 + ln*8) = lv;
            }
        }
    }
}

// K2: MFMA fast pass + fused quarter-merge (last block of each rgrp).
__global__ __launch_bounds__(256, 4)
void vq_argmin_mfma(const short* __restrict__ zt_hi, const short* __restrict__ zt_lo,
                    const short* __restrict__ efrag, const float* __restrict__ b2,
                    float* __restrict__ p_b1v, float* __restrict__ p_b2v,
                    int* __restrict__ p_b1i, int* __restrict__ rgrp_ctr,
                    int* __restrict__ idx, float* __restrict__ out,
                    int* __restrict__ counts, int* __restrict__ fcnt,
                    int* __restrict__ flist) {
    __shared__ __align__(16) char lds[2][16384];
    __shared__ int amLast;
    const int tid  = threadIdx.x;
    const int lane = tid & 63;
    const int wid  = tid >> 6;
    const int blk  = blockIdx.x;
    const int quar = blk & 3;
    const int rgrp = blk >> 2;
    const int n0   = rgrp * 128 + wid * 32;
    const int lcol = lane & 15;
    const int kq   = lane >> 4;

    s16x8 a_h[2][2], a_l[2][2];
#pragma unroll
    for (int rt = 0; rt < 2; ++rt) {
        const short* zh = zt_hi + (size_t)(n0 + rt*16 + lcol) * DIMV + kq*8;
        const short* zl = zt_lo + (size_t)(n0 + rt*16 + lcol) * DIMV + kq*8;
        a_h[rt][0] = *(const s16x8*)(zh);
        a_h[rt][1] = *(const s16x8*)(zh + 32);
        a_l[rt][0] = *(const s16x8*)(zl);
        a_l[rt][1] = *(const s16x8*)(zl + 32);
    }

    float b1v[2][4], b2v[2][4]; int b1i[2][4];
#pragma unroll
    for (int rt = 0; rt < 2; ++rt)
#pragma unroll
        for (int r = 0; r < 4; ++r) { b1v[rt][r] = 3.4e38f; b2v[rt][r] = 3.4e38f; b1i[rt][r] = 0; }

    const int c0 = quar * 32;
    const char* gbase = (const char*)efrag;
    {
        const char* src = gbase + (size_t)c0 * 16384 + tid * 16;
        char* dst = &lds[0][tid * 16];
#pragma unroll
        for (int i = 0; i < 4; ++i) gl_lds16(src + i * 4096, dst + i * 4096);
    }

    for (int t = 0; t < 32; ++t) {
        __syncthreads();
        if (t < 31) {
            const char* src = gbase + (size_t)(c0 + t + 1) * 16384 + tid * 16;
            char* dst = &lds[(t + 1) & 1][tid * 16];
#pragma unroll
            for (int i = 0; i < 4; ++i) gl_lds16(src + i * 4096, dst + i * 4096);
        }
        const char* base = lds[t & 1];
        s16x8 B[16];
#pragma unroll
        for (int f = 0; f < 16; ++f)
            B[f] = *(const s16x8*)(base + f*1024 + lane*16);

        const int kt = (c0 + t) * 64;
        float b2f[4];
#pragma unroll
        for (int ct = 0; ct < 4; ++ct) b2f[ct] = b2[kt + ct*16 + lcol];

#pragma unroll
        for (int ct = 0; ct < 4; ++ct) {
            const int code = kt + ct*16 + lcol;
#pragma unroll
            for (int rt = 0; rt < 2; ++rt) {
                f32x4 acc = {b2f[ct], b2f[ct], b2f[ct], b2f[ct]};
                acc = __builtin_amdgcn_mfma_f32_16x16x32_bf16(a_h[rt][0], B[ct*4+0], acc, 0, 0, 0);
                acc = __builtin_amdgcn_mfma_f32_16x16x32_bf16(a_h[rt][1], B[ct*4+2], acc, 0, 0, 0);
                acc = __builtin_amdgcn_mfma_f32_16x16x32_bf16(a_l[rt][0], B[ct*4+0], acc, 0, 0, 0);
                acc = __builtin_amdgcn_mfma_f32_16x16x32_bf16(a_l[rt][1], B[ct*4+2], acc, 0, 0, 0);
                acc = __builtin_amdgcn_mfma_f32_16x16x32_bf16(a_h[rt][0], B[ct*4+1], acc, 0, 0, 0);
                acc = __builtin_amdgcn_mfma_f32_16x16x32_bf16(a_h[rt][1], B[ct*4+3], acc, 0, 0, 0);
#pragma unroll
                for (int r = 0; r < 4; ++r) {
                    const float v = acc[r];
                    b2v[rt][r] = __builtin_amdgcn_fmed3f(v, b1v[rt][r], b2v[rt][r]);
                    const bool lt = (v < b1v[rt][r]);
                    b1i[rt][r] = lt ? code : b1i[rt][r];
                    b1v[rt][r] = fminf(v, b1v[rt][r]);
                }
            }
        }
    }

#pragma unroll
    for (int m = 8; m >= 1; m >>= 1) {
#pragma unroll
        for (int rt = 0; rt < 2; ++rt)
#pragma unroll
            for (int r = 0; r < 4; ++r) {
                const float ov1 = __shfl_xor(b1v[rt][r], m);
                const int   oi1 = __shfl_xor(b1i[rt][r], m);
                const float ov2 = __shfl_xor(b2v[rt][r], m);
                const bool take = (ov1 < b1v[rt][r]) || (ov1 == b1v[rt][r] && oi1 < b1i[rt][r]);
                const float nb2 = take ? fminf(b1v[rt][r], ov2) : fminf(b2v[rt][r], ov1);
                if (take) { b1v[rt][r] = ov1; b1i[rt][r] = oi1; }
                b2v[rt][r] = nb2;
            }
    }
    if (lcol == 0) {
#pragma unroll
        for (int rt = 0; rt < 2; ++rt)
#pragma unroll
            for (int r = 0; r < 4; ++r) {
                const int n = n0 + rt*16 + kq*4 + r;
                p_b1v[quar * 32768 + n] = b1v[rt][r];
                p_b2v[quar * 32768 + n] = b2v[rt][r];
                p_b1i[quar * 32768 + n] = b1i[rt][r];
            }
    }

    // ---- fused merge: last quarter-block of this rgrp merges 128 rows ----
    __threadfence();                          // release our partials
    __syncthreads();
    if (tid == 0) amLast = (atomicAdd(&rgrp_ctr[rgrp], 1) == 3) ? 1 : 0;
    __syncthreads();
    if (amLast) {
        __threadfence();                      // acquire others' partials
        if (tid < 128) {
            const int n = rgrp * 128 + tid;
            float b1 = p_b1v[n], sec = p_b2v[n];
            int   bi = p_b1i[n];
#pragma unroll
            for (int q = 1; q < 4; ++q) {
                const float v = p_b1v[q * 32768 + n];
                const float s = p_b2v[q * 32768 + n];
                const int   i = p_b1i[q * 32768 + n];
                const bool take = (v < b1);   // earlier quarter wins ties
                sec = take ? fminf(b1, s) : fminf(sec, v);
                b1  = take ? v : b1;
                bi  = take ? i : bi;
            }
            idx[n] = bi;
            out[IDX_OFF + n] = (float)bi;
            atomicAdd(&counts[bi], 1);
            const int fl = (sec - b1 < MARGIN) ? 1 : 0;
            ((int*)p_b2v)[n] = fl;            // flag[] overlays dead q=0 seconds
            if (fl) {
                const int p = atomicAdd(fcnt, 1);
                flist[p] = n;
            }
        }
    }
}

// K3: np-emulated re-rank for flagged rows, job = (row, K-quarter).
// a2 computed locally from zsh (same pairwise-8 order as before).
__global__ __launch_bounds__(256)
void vq_refine1(const float* __restrict__ z_e, const float* __restrict__ emb,
                const float* __restrict__ b2, const int* __restrict__ fcnt,
                const int* __restrict__ flist,
                float* __restrict__ pq_v, int* __restrict__ pq_i) {
    __shared__ float  es[128][65];
    __shared__ float  zsh[64];
    __shared__ double pd[128];
    __shared__ float  bv[128];
    __shared__ int    bix[128];
    const int tid = threadIdx.x;
    const int cnt = *fcnt;
    const int njobs = cnt * 4;
    const int c  = tid & 127;
    const int hh = tid >> 7;
    const int dh = hh * 32;

    for (int j = blockIdx.x; j < njobs; j += gridDim.x) {
        const int it = j >> 2, q = j & 3;
        const int n  = flist[it];
        const int b = n >> 12, h = (n >> 6) & 63, w = n & 63;
        __syncthreads();
        if (tid < 64) zsh[tid] = z_e[(((b << 6) + tid) << 12) + (h << 6) + w];
        __syncthreads();

        const float a2n = pairwise8_sq(zsh);   // numpy-exact, from staged row
        float zreg[32];
#pragma unroll
        for (int i = 0; i < 32; ++i) zreg[i] = zsh[dh + i];

        float best = 3.4e38f;
        int   bi   = 0;
        const int kbase = q * 2048;
        for (int t = 0; t < 16; ++t) {
            const int kt = kbase + t * 128;
            __syncthreads();
#pragma unroll
            for (int i = 0; i < 8; ++i) {
                const int g  = i * 256 + tid;
                const int cc = g >> 4, dd = (g & 15) * 4;
                const float4 v = *(const float4*)(emb + (size_t)(kt + cc) * DIMV + dd);
                es[cc][dd + 0] = v.x; es[cc][dd + 1] = v.y;
                es[cc][dd + 2] = v.z; es[cc][dd + 3] = v.w;
            }
            __syncthreads();

            double s0 = 0.0, s1 = 0.0, s2 = 0.0, s3 = 0.0;
#pragma unroll
            for (int i = 0; i < 32; i += 4) {
                s0 += (double)zreg[i + 0] * (double)es[c][dh + i + 0];
                s1 += (double)zreg[i + 1] * (double)es[c][dh + i + 1];
                s2 += (double)zreg[i + 2] * (double)es[c][dh + i + 2];
                s3 += (double)zreg[i + 3] * (double)es[c][dh + i + 3];
            }
            const double sh = (s0 + s1) + (s2 + s3);
            if (hh == 1) pd[c] = sh;
            __syncthreads();
            if (hh == 0) {
                const double full = sh + pd[c];
                const float qab  = (float)full;            // sgemm proxy
                const float m2ab = __fmul_rn(-2.0f, qab);
                const float t1   = __fadd_rn(a2n, m2ab);
                const float dist = __fadd_rn(t1, b2[kt + c]);
                if (dist < best) { best = dist; bi = kt + c; }
            }
        }
        if (hh == 0) { bv[c] = best; bix[c] = bi; }
        __syncthreads();
#pragma unroll
        for (int s = 64; s > 0; s >>= 1) {
            if (tid < s) {
                const float ov = bv[tid + s];
                const int   oi = bix[tid + s];
                if (ov < bv[tid] || (ov == bv[tid] && oi < bix[tid])) { bv[tid] = ov; bix[tid] = oi; }
            }
            __syncthreads();
        }
        if (tid == 0) { pq_v[q * 32768 + n] = bv[0]; pq_i[q * 32768 + n] = bix[0]; }
    }
}

// K4: patch flagged rows + z_q gather + loss; last block computes stats.
__global__ __launch_bounds__(256)
void vq_quant(const float* __restrict__ z_e, const float* __restrict__ emb,
              int* __restrict__ idx, const float* __restrict__ pq_v,
              const int* __restrict__ pq_i, float* __restrict__ out,
              int* __restrict__ counts, float* __restrict__ loss,
              int* __restrict__ done_ctr) {
    __shared__ float q[64][65];
    __shared__ float red[256];
    __shared__ float ruse[256];
    __shared__ int amLast;
    const int tid = threadIdx.x;
    const int blk = blockIdx.x;
    const int b = blk >> 6, h = blk & 63;

    // phase A: patch this tile's flagged rows from np-refine partials
    if (tid < 64) {
        const int n = blk * 64 + tid;
        if (((const int*)pq_v)[32768 * 0 + 0 == 0 ? n : n]) { /* flag read below */ }
        const int fl = ((const int*)(pq_v + 32768))[n - 32768 >= 0 ? 0 : 0];  // placeholder avoided
    }
    // (clean version of phase A)
    if (tid < 64) {
        const int n = blk * 64 + tid;
        // flag[] lives in p_b2v head == (pq_v + 32768*? ) -- passed explicitly below
    }
    __syncthreads();

    // phase B: gather + loss
    {
        const int r = tid >> 2, qd = (tid & 3) * 16;
        const int code = idx[blk * 64 + r];
        const float4* er = (const float4*)(emb + code * DIMV + qd);
#pragma unroll
        for (int i = 0; i < 4; ++i) {
            const float4 e4 = er[i];
            q[r][qd + i*4 + 0] = e4.x;
            q[r][qd + i*4 + 1] = e4.y;
            q[r][qd + i*4 + 2] = e4.z;
            q[r][qd + i*4 + 3] = e4.w;
        }
    }
    __syncthreads();
    const int w = tid & 63, dq = tid >> 6;
    float dl = 0.f;
#pragma unroll
    for (int i = 0; i < 16; ++i) {
        const int d = dq * 16 + i;
        const int g = ((b * 64 + d) << 12) + (h << 6) + w;
        const float qq = q[w][d];
        const float zz = z_e[g];
        out[g] = qq;
        const float df = zz - qq;
        dl = fmaf(df, df, dl);
    }
    red[tid] = dl;
    __syncthreads();
#pragma unroll
    for (int s = 128; s > 0; s >>= 1) {
        if (tid < s) red[tid] += red[tid + s];
        __syncthreads();
    }
    if (tid == 0) atomicAdd(loss, red[0]);

    // phase C: last block computes stats
    __threadfence();
    __syncthreads();
    if (tid == 0) amLast = (atomicAdd(done_ctr, 1) == 511) ? 1 : 0;
    __syncthreads();
    if (amLast) {
        __threadfence();
        float* rent = (float*)q;               // reuse smem
        float ent = 0.f, used = 0.f;
        for (int k = tid; k < K_CODES; k += 256) {
            const int c = atomicAdd(&counts[k], 0);   // device-coherent read
            if (c > 0) {
                const float avg = (float)c * (1.0f / 32768.0f);
                ent  += avg * logf(avg + 1e-10f);
                used += 1.0f;
            }
        }
        rent[tid] = ent;
        ruse[tid] = used;
        __syncthreads();
#pragma unroll
        for (int s = 128; s > 0; s >>= 1) {
            if (tid < s) {
                rent[tid] += rent[tid + s];
                ruse[tid] += ruse[tid + s];
            }
            __syncthreads();
        }
        if (tid == 0) {
            const float lv = atomicAdd(loss, 0.0f);
            out[SCAL_OFF + 0] = 0.25f * lv * (1.0f / 2097152.0f);
            out[SCAL_OFF + 1] = expf(-rent[0]);
            out[SCAL_OFF + 2] = ruse[0] * (1.0f / 8192.0f);
        }
    }
}

// K4-pre: tiny patch pass has been folded into vq_quant via flag/pq pointers.
// To keep phase A clean, it is implemented here as a separate device function
// call was avoided; instead vq_quant_patch handles it inline before gather.
__global__ __launch_bounds__(256)
void vq_patch(const int* __restrict__ flag, const float* __restrict__ pq_v,
              const int* __restrict__ pq_i, int* __restrict__ idx,
              float* __restrict__ out, int* __restrict__ counts) {
    const int n = blockIdx.x * 256 + threadIdx.x;
    if (n >= 32768) return;
    if (!flag[n]) return;
    float best = pq_v[n];
    int   bi   = pq_i[n];
#pragma unroll
    for (int q2 = 1; q2 < 4; ++q2) {
        const float v = pq_v[q2 * 32768 + n];
        if (v < best) { best = v; bi = pq_i[q2 * 32768 + n]; }
    }
    const int oldbi = idx[n];
    if (bi != oldbi) {
        idx[n] = bi;
        out[IDX_OFF + n] = (float)bi;
        atomicSub(&counts[oldbi], 1);
        atomicAdd(&counts[bi], 1);
    }
}

extern "C" void kernel_launch(void* const* d_in, const int* in_sizes, int n_in,
                              void* d_out, int out_size, void* d_ws, size_t ws_size,
                              hipStream_t stream) {
    const float* z_e = (const float*)d_in[0];
    const float* emb = (const float*)d_in[1];
    float* out = (float*)d_out;
    char*  ws  = (char*)d_ws;

    float* b2     = (float*)(ws + WS_B2);
    int*   idx    = (int*)(ws + WS_IDX);
    int*   counts = (int*)(ws + WS_CNT);
    float* loss   = (float*)(ws + WS_LOSS);
    int*   fcnt   = (int*)(ws + WS_FCNT);
    int*   done   = (int*)(ws + WS_DONE);
    int*   flist  = (int*)(ws + WS_FLIST);
    int*   rgrp   = (int*)(ws + WS_RGRP);
    short* efrag  = (short*)(ws + WS_EFRAG);
    short* zt_hi  = (short*)(ws + WS_ZHI);
    short* zt_lo  = (short*)(ws + WS_ZLO);
    float* p_b1v  = (float*)(ws + WS_P1V);
    float* p_b2v  = (float*)(ws + WS_P2V);
    int*   p_b1i  = (int*)(ws + WS_P1I);
    int*   flag   = (int*)(ws + WS_P2V);       // flag[] overlays p_b2v head

    hipLaunchKernelGGL(vq_prep,        dim3(576),  dim3(256), 0, stream,
                       z_e, emb, b2, zt_hi, zt_lo, efrag, counts, rgrp);
    hipLaunchKernelGGL(vq_argmin_mfma, dim3(1024), dim3(256), 0, stream,
                       zt_hi, zt_lo, efrag, b2, p_b1v, p_b2v, p_b1i,
                       rgrp, idx, out, counts, fcnt, flist);
    hipLaunchKernelGGL(vq_refine1,     dim3(1024), dim3(256), 0, stream,
                       z_e, emb, b2, fcnt, flist, p_b1v, p_b1i);
    hipLaunchKernelGGL(vq_patch,       dim3(128),  dim3(256), 0, stream,
                       flag, p_b1v, p_b1i, idx, out, counts);
    hipLaunchKernelGGL(vq_quant,       dim3(512),  dim3(256), 0, stream,
                       z_e, emb, idx, p_b1v, p_b1i, out, counts, loss, done);
}